// Round 1
// baseline (404.686 us; speedup 1.0000x reference)
//
#include <hip/hip_runtime.h>

#define NB 4
#define NL 1024
#define NH 16
#define ND 1024
#define HD 64
#define FMIN_F32 (-3.4028234663852886e38f)

// ---------------------------------------------------------------------------
// Kernel 1: row sums of query/key/value: out[tensor][b*NL+row] = sum_c in[row][c]
// One wave per 1024-float row; 3*4096 rows total.
// ---------------------------------------------------------------------------
__global__ __launch_bounds__(256)
void rowsum_kernel(const float* __restrict__ q, const float* __restrict__ k,
                   const float* __restrict__ v, float* __restrict__ out) {
    int gw   = blockIdx.x * 4 + (threadIdx.x >> 6);
    int lane = threadIdx.x & 63;
    int tensor = gw >> 12;       // 0,1,2
    int row    = gw & 4095;      // 0..NB*NL-1
    const float* src = tensor == 0 ? q : (tensor == 1 ? k : v);
    const float* p = src + (size_t)row * ND;
    float s = 0.f;
#pragma unroll
    for (int t = 0; t < 4; ++t) {
        float4 x = *reinterpret_cast<const float4*>(p + t * 256 + lane * 4);
        s += (x.x + x.y) + (x.z + x.w);
    }
#pragma unroll
    for (int off = 32; off; off >>= 1) s += __shfl_xor(s, off);
    if (lane == 0) out[tensor * (NB * NL) + row] = s;
}

// ---------------------------------------------------------------------------
// Kernel 2: fused G + batch-softmax + PV.
// Grid (16 i-tiles, 16 heads). Block 256 threads, TI=TJ=64.
// heads[b][h][i][t] = sum_j softmax_b(qsum[b,i]*ksum[b,j]*G[h,i,j]/4 masked)
//                     * vsum[b,j] * v_w[h,j,t]
// ---------------------------------------------------------------------------
__global__ __launch_bounds__(256)
void attn_kernel(const float* __restrict__ q_w, const float* __restrict__ k_w,
                 const float* __restrict__ v_w, const int* __restrict__ pad,
                 const float* __restrict__ sums, float* __restrict__ heads) {
    constexpr int TI = 64, TJ = 64;
    __shared__ __align__(16) float qwT[HD][TI + 4];   // [s][i]
    __shared__ __align__(16) float kwT[HD][TJ + 4];   // [s][jj]
    __shared__ __align__(16) float vw[TJ][HD + 4];    // [jj][t]
    __shared__ float4 wlds[TI][TJ + 1];               // [i][jjx] permuted: jjx=(jl&3)*16+(jl>>2)
    __shared__ float qsL[NB][TI];
    __shared__ float ksL[NB][TJ];
    __shared__ float vsL[NB][TJ];
    __shared__ int   pmL[NB][TJ];

    const float* qsum = sums;
    const float* ksum = sums + NB * NL;
    const float* vsum = sums + 2 * NB * NL;

    const int it0 = blockIdx.x * TI;
    const int h   = blockIdx.y;
    const int tid = threadIdx.x;

    const int r4  = tid >> 2;          // 0..63: row for staging loads
    const int s16 = (tid & 3) * 16;    // s-range start for staging loads

    // ---- load q_w tile transposed (once) + qsum slice ----
#pragma unroll
    for (int t = 0; t < 4; ++t) {
        int s = s16 + t * 4;
        float4 x = *reinterpret_cast<const float4*>(
            q_w + ((size_t)(h * NL + it0 + r4)) * HD + s);
        qwT[s + 0][r4] = x.x; qwT[s + 1][r4] = x.y;
        qwT[s + 2][r4] = x.z; qwT[s + 3][r4] = x.w;
    }
    {
        int b = tid >> 6, i = tid & 63;
        qsL[b][i] = qsum[b * NL + it0 + i];
    }

    // G-phase mapping: 4x4 sub-tile per thread
    const int gi0 = (tid >> 4) << 2;   // 0,4,..,60
    const int gj0 = (tid & 15) << 2;   // 0,4,..,60
    const int qlo = tid & 15;          // column index component for permuted wlds
    // PV mapping: one i-row, 16 t's per thread
    const int pi  = tid >> 2;          // 0..63
    const int pt0 = (tid & 3) * 16;

    float4 acc[NB][4];
#pragma unroll
    for (int b = 0; b < NB; ++b)
#pragma unroll
        for (int t = 0; t < 4; ++t) acc[b][t] = make_float4(0.f, 0.f, 0.f, 0.f);

    for (int jt = 0; jt < NL / TJ; ++jt) {
        const int j0 = jt * TJ;
        __syncthreads();   // previous iteration's PV reads done before overwrite

        // ---- stage k_w (transposed), v_w (direct), ksum/vsum/pad slices ----
#pragma unroll
        for (int t = 0; t < 4; ++t) {
            int s = s16 + t * 4;
            const size_t base = ((size_t)(h * NL + j0 + r4)) * HD + s;
            float4 x = *reinterpret_cast<const float4*>(k_w + base);
            kwT[s + 0][r4] = x.x; kwT[s + 1][r4] = x.y;
            kwT[s + 2][r4] = x.z; kwT[s + 3][r4] = x.w;
            float4 y = *reinterpret_cast<const float4*>(v_w + base);
            *reinterpret_cast<float4*>(&vw[r4][s]) = y;
        }
        {
            int b = tid >> 6, jj = tid & 63;
            ksL[b][jj] = ksum[b * NL + j0 + jj];
            vsL[b][jj] = vsum[b * NL + j0 + jj];
            pmL[b][jj] = pad[b * NL + j0 + jj];
        }
        __syncthreads();

        // ---- G: 4x4 dot-products of length 64 ----
        float g[4][4];
#pragma unroll
        for (int a = 0; a < 4; ++a)
#pragma unroll
            for (int c = 0; c < 4; ++c) g[a][c] = 0.f;
#pragma unroll 8
        for (int s = 0; s < HD; ++s) {
            float4 qa = *reinterpret_cast<const float4*>(&qwT[s][gi0]);
            float4 kb = *reinterpret_cast<const float4*>(&kwT[s][gj0]);
            float ar[4] = {qa.x, qa.y, qa.z, qa.w};
            float br[4] = {kb.x, kb.y, kb.z, kb.w};
#pragma unroll
            for (int a = 0; a < 4; ++a)
#pragma unroll
                for (int c = 0; c < 4; ++c) g[a][c] = fmaf(ar[a], br[c], g[a][c]);
        }

        // ---- batch softmax -> weights (weight * vsum folded), permuted store ----
#pragma unroll
        for (int a = 0; a < 4; ++a) {
            const int il = gi0 + a;
            const int ig = it0 + il;
            const float qs0 = qsL[0][il], qs1 = qsL[1][il];
            const float qs2 = qsL[2][il], qs3 = qsL[3][il];
#pragma unroll
            for (int c = 0; c < 4; ++c) {
                const int jl = gj0 + c;
                const int jg = j0 + jl;
                const float gv = g[a][c] * 0.25f;   // / sqrt(H)=4
                const bool causal = jg > ig;
                const float sb0 = (causal || pmL[0][jl]) ? FMIN_F32 : qs0 * ksL[0][jl] * gv;
                const float sb1 = (causal || pmL[1][jl]) ? FMIN_F32 : qs1 * ksL[1][jl] * gv;
                const float sb2 = (causal || pmL[2][jl]) ? FMIN_F32 : qs2 * ksL[2][jl] * gv;
                const float sb3 = (causal || pmL[3][jl]) ? FMIN_F32 : qs3 * ksL[3][jl] * gv;
                const float mx = fmaxf(fmaxf(sb0, sb1), fmaxf(sb2, sb3));
                // all-masked: sb-mx==0 -> e=1 each -> 0.25 weights (matches nan_to_num ref)
                const float e0 = __expf(sb0 - mx);
                const float e1 = __expf(sb1 - mx);
                const float e2 = __expf(sb2 - mx);
                const float e3 = __expf(sb3 - mx);
                const float inv = 1.0f / (e0 + e1 + e2 + e3);
                float4 w4;
                w4.x = e0 * inv * vsL[0][jl];
                w4.y = e1 * inv * vsL[1][jl];
                w4.z = e2 * inv * vsL[2][jl];
                w4.w = e3 * inv * vsL[3][jl];
                wlds[il][c * 16 + qlo] = w4;   // jjx = (jl&3)*16 + (jl>>2)
            }
        }
        __syncthreads();

        // ---- PV: acc[b][t] += w[b,i,jj] * vw[jj][t] ----
#pragma unroll 8
        for (int jjx = 0; jjx < TJ; ++jjx) {
            const int jj = ((jjx & 15) << 2) | (jjx >> 4);  // inverse permutation
            float4 w4 = wlds[pi][jjx];
            float wr[4] = {w4.x, w4.y, w4.z, w4.w};
            float4 vv[4];
            vv[0] = *reinterpret_cast<const float4*>(&vw[jj][pt0]);
            vv[1] = *reinterpret_cast<const float4*>(&vw[jj][pt0 + 4]);
            vv[2] = *reinterpret_cast<const float4*>(&vw[jj][pt0 + 8]);
            vv[3] = *reinterpret_cast<const float4*>(&vw[jj][pt0 + 12]);
#pragma unroll
            for (int b = 0; b < 4; ++b)
#pragma unroll
                for (int t = 0; t < 4; ++t) {
                    acc[b][t].x = fmaf(wr[b], vv[t].x, acc[b][t].x);
                    acc[b][t].y = fmaf(wr[b], vv[t].y, acc[b][t].y);
                    acc[b][t].z = fmaf(wr[b], vv[t].z, acc[b][t].z);
                    acc[b][t].w = fmaf(wr[b], vv[t].w, acc[b][t].w);
                }
        }
    }

    // ---- store heads[b][h][it0+pi][pt0..pt0+15] ----
#pragma unroll
    for (int b = 0; b < NB; ++b) {
        float* dst = heads + ((size_t)((b * NH + h) * NL) + it0 + pi) * HD + pt0;
#pragma unroll
        for (int t = 0; t < 4; ++t)
            *reinterpret_cast<float4*>(dst + 4 * t) = acc[b][t];
    }
}

// ---------------------------------------------------------------------------
// Kernel 3: out[b] = heads2[b](1024x1024, == heads[b] flat) @ o_w(1024x1024)
// 128x128 tile, 8x8 per thread, K-tile 32.
// ---------------------------------------------------------------------------
__global__ __launch_bounds__(256)
void outgemm_kernel(const float* __restrict__ heads, const float* __restrict__ o_w,
                    float* __restrict__ out) {
    constexpr int BT = 128, KT = 32;
    __shared__ __align__(16) float aT[KT][BT + 4];  // [k][i]
    __shared__ __align__(16) float bl[KT][BT + 4];  // [k][o]
    const int b  = blockIdx.z;
    const int i0 = blockIdx.y * BT;
    const int o0 = blockIdx.x * BT;
    const int tid = threadIdx.x;
    const int ty = tid >> 4, tx = tid & 15;
    const float* A = heads + (size_t)b * NL * ND;
    float acc[8][8];
#pragma unroll
    for (int r = 0; r < 8; ++r)
#pragma unroll
        for (int c = 0; c < 8; ++c) acc[r][c] = 0.f;

    for (int kt = 0; kt < ND / KT; ++kt) {
        const int k0 = kt * KT;
        __syncthreads();
        {   // A tile: 128 rows x 32 k, transposed into aT
            int r  = tid >> 1;
            int kc = (tid & 1) * 16;
#pragma unroll
            for (int t = 0; t < 4; ++t) {
                int kk = kc + t * 4;
                float4 x = *reinterpret_cast<const float4*>(
                    A + (size_t)(i0 + r) * ND + k0 + kk);
                aT[kk + 0][r] = x.x; aT[kk + 1][r] = x.y;
                aT[kk + 2][r] = x.z; aT[kk + 3][r] = x.w;
            }
            // B tile: 32 k x 128 o, direct
            int kk = tid >> 3;
            int oc = (tid & 7) * 16;
#pragma unroll
            for (int t = 0; t < 4; ++t) {
                float4 x = *reinterpret_cast<const float4*>(
                    o_w + (size_t)(k0 + kk) * ND + o0 + oc + t * 4);
                *reinterpret_cast<float4*>(&bl[kk][oc + t * 4]) = x;
            }
        }
        __syncthreads();
#pragma unroll
        for (int k = 0; k < KT; ++k) {
            float4 a0 = *reinterpret_cast<const float4*>(&aT[k][ty * 8]);
            float4 a1 = *reinterpret_cast<const float4*>(&aT[k][ty * 8 + 4]);
            float4 b0 = *reinterpret_cast<const float4*>(&bl[k][tx * 8]);
            float4 b1 = *reinterpret_cast<const float4*>(&bl[k][tx * 8 + 4]);
            float ar[8] = {a0.x, a0.y, a0.z, a0.w, a1.x, a1.y, a1.z, a1.w};
            float br[8] = {b0.x, b0.y, b0.z, b0.w, b1.x, b1.y, b1.z, b1.w};
#pragma unroll
            for (int r = 0; r < 8; ++r)
#pragma unroll
                for (int c = 0; c < 8; ++c) acc[r][c] = fmaf(ar[r], br[c], acc[r][c]);
        }
    }
#pragma unroll
    for (int r = 0; r < 8; ++r) {
        float* dst = out + (size_t)b * NL * ND + (size_t)(i0 + ty * 8 + r) * ND + o0 + tx * 8;
        *reinterpret_cast<float4*>(dst)     = make_float4(acc[r][0], acc[r][1], acc[r][2], acc[r][3]);
        *reinterpret_cast<float4*>(dst + 4) = make_float4(acc[r][4], acc[r][5], acc[r][6], acc[r][7]);
    }
}

// ---------------------------------------------------------------------------
extern "C" void kernel_launch(void* const* d_in, const int* in_sizes, int n_in,
                              void* d_out, int out_size, void* d_ws, size_t ws_size,
                              hipStream_t stream) {
    const float* query = (const float*)d_in[0];
    const float* key   = (const float*)d_in[1];
    const float* value = (const float*)d_in[2];
    const int*   pad   = (const int*)d_in[3];
    const float* q_w   = (const float*)d_in[4];
    const float* k_w   = (const float*)d_in[5];
    const float* v_w   = (const float*)d_in[6];
    const float* o_w   = (const float*)d_in[7];
    float* out = (float*)d_out;

    float* ws    = (float*)d_ws;
    float* sums  = ws;              // 3 * NB*NL floats (qsum, ksum, vsum)
    float* heads = ws + 16384;      // NB*NH*NL*HD = 4M floats (16 MB)

    rowsum_kernel<<<3 * (NB * NL) / 4, 256, 0, stream>>>(query, key, value, sums);

    dim3 ag(NL / 64, NH);
    attn_kernel<<<ag, 256, 0, stream>>>(q_w, k_w, v_w, pad, sums, heads);

    dim3 og(ND / 128, NL / 128, NB);
    outgemm_kernel<<<og, 256, 0, stream>>>(heads, o_w, out);
}

// Round 2
// 179.948 us; speedup vs baseline: 2.2489x; 2.2489x over previous
//
#include <hip/hip_runtime.h>
#include <hip/hip_bf16.h>

#define NB 4
#define NL 1024
#define NH 16
#define ND 1024
#define HD 64
#define FMIN_F32 (-3.4028234663852886e38f)

typedef __bf16 bf16x8 __attribute__((ext_vector_type(8)));
typedef float f32x4 __attribute__((ext_vector_type(4)));

static __device__ inline unsigned short f2bf(float f) {
    __hip_bfloat16 h = __float2bfloat16(f);
    return __builtin_bit_cast(unsigned short, h);
}

// ---------------------------------------------------------------------------
// Kernel 1: row sums of query/key/value.
// ---------------------------------------------------------------------------
__global__ __launch_bounds__(256)
void rowsum_kernel(const float* __restrict__ q, const float* __restrict__ k,
                   const float* __restrict__ v, float* __restrict__ out) {
    int gw   = blockIdx.x * 4 + (threadIdx.x >> 6);
    int lane = threadIdx.x & 63;
    int tensor = gw >> 12;
    int row    = gw & 4095;
    const float* src = tensor == 0 ? q : (tensor == 1 ? k : v);
    const float* p = src + (size_t)row * ND;
    float s = 0.f;
#pragma unroll
    for (int t = 0; t < 4; ++t) {
        float4 x = *reinterpret_cast<const float4*>(p + t * 256 + lane * 4);
        s += (x.x + x.y) + (x.z + x.w);
    }
#pragma unroll
    for (int off = 32; off; off >>= 1) s += __shfl_xor(s, off);
    if (lane == 0) out[tensor * (NB * NL) + row] = s;
}

// ---------------------------------------------------------------------------
// Kernel 2: transpose k_w -> k_wT (f32 [h][s][j]) and v_w -> v_wT (bf16 [h][t][j])
// ---------------------------------------------------------------------------
__global__ __launch_bounds__(256)
void transKV_kernel(const float* __restrict__ k_w, const float* __restrict__ v_w,
                    float* __restrict__ k_wT, unsigned short* __restrict__ v_wT) {
    __shared__ float tile[64][68];
    const int j0 = blockIdx.x * 64;
    const int h  = blockIdx.y;
    const int tid = threadIdx.x;
#pragma unroll
    for (int t = 0; t < 4; ++t) {
        int id = tid + 256 * t;
        int j = id >> 4, s4 = (id & 15) * 4;
        *(float4*)&tile[j][s4] =
            *(const float4*)(k_w + ((size_t)(h * NL + j0 + j)) * HD + s4);
    }
    __syncthreads();
#pragma unroll
    for (int t = 0; t < 4; ++t) {
        int id = tid + 256 * t;
        int s = id >> 4, j4 = (id & 15) * 4;
        float4 y;
        y.x = tile[j4 + 0][s]; y.y = tile[j4 + 1][s];
        y.z = tile[j4 + 2][s]; y.w = tile[j4 + 3][s];
        *(float4*)(k_wT + ((size_t)(h * HD + s)) * NL + j0 + j4) = y;
    }
    __syncthreads();
#pragma unroll
    for (int t = 0; t < 4; ++t) {
        int id = tid + 256 * t;
        int j = id >> 4, s4 = (id & 15) * 4;
        *(float4*)&tile[j][s4] =
            *(const float4*)(v_w + ((size_t)(h * NL + j0 + j)) * HD + s4);
    }
    __syncthreads();
#pragma unroll
    for (int t = 0; t < 4; ++t) {
        int id = tid + 256 * t;
        int s = id >> 4, j4 = (id & 15) * 4;
        ushort4 u;
        u.x = f2bf(tile[j4 + 0][s]); u.y = f2bf(tile[j4 + 1][s]);
        u.z = f2bf(tile[j4 + 2][s]); u.w = f2bf(tile[j4 + 3][s]);
        *(ushort4*)(v_wT + ((size_t)(h * HD + s)) * NL + j0 + j4) = u;
    }
}

// ---------------------------------------------------------------------------
// Kernel 3: o_w [c][o] -> o_wT bf16 [o][c]
// ---------------------------------------------------------------------------
__global__ __launch_bounds__(256)
void transO_kernel(const float* __restrict__ o_w, unsigned short* __restrict__ o_wT) {
    __shared__ float tile[64][68];
    const int c0 = blockIdx.x * 64;
    const int o0 = blockIdx.y * 64;
    const int tid = threadIdx.x;
#pragma unroll
    for (int t = 0; t < 4; ++t) {
        int id = tid + 256 * t;
        int c = id >> 4, o4 = (id & 15) * 4;
        *(float4*)&tile[c][o4] =
            *(const float4*)(o_w + ((size_t)(c0 + c)) * ND + o0 + o4);
    }
    __syncthreads();
#pragma unroll
    for (int t = 0; t < 4; ++t) {
        int id = tid + 256 * t;
        int o = id >> 4, c4 = (id & 15) * 4;
        ushort4 u;
        u.x = f2bf(tile[c4 + 0][o]); u.y = f2bf(tile[c4 + 1][o]);
        u.z = f2bf(tile[c4 + 2][o]); u.w = f2bf(tile[c4 + 3][o]);
        *(ushort4*)(o_wT + ((size_t)(o0 + o)) * ND + c0 + c4) = u;
    }
}

// ---------------------------------------------------------------------------
// Kernel 4: fused G (f32) + batch-softmax (f32) + PV (bf16 MFMA).
// Grid (32 i-tiles, 16 heads), 256 threads. TI=32, TJ=64.
// Writes heads directly in out-GEMM A layout: headsA[b][h*64 + i>>4][(i&15)*64 + t]
// ---------------------------------------------------------------------------
__global__ __launch_bounds__(256, 2)
void attn_kernel(const float* __restrict__ q_w, const int* __restrict__ pad,
                 const float* __restrict__ sums, const float* __restrict__ k_wT,
                 const unsigned short* __restrict__ v_wT,
                 unsigned short* __restrict__ headsA) {
    constexpr int TI = 32, TJ = 64;
    __shared__ float qwT[HD][TI + 4];                      // [s][i]
    __shared__ float kwT[HD][TJ + 4];                      // [s][j]
    __shared__ __align__(16) unsigned short vTl[TJ * TJ];  // [t][j] bf16, XOR-swizzled
    __shared__ __align__(16) unsigned short wlds[NB * TI * TJ]; // [b][i][j] bf16, XOR-swizzled
    __shared__ float qsL[NB][TI];
    __shared__ float ksL[NB][TJ];
    __shared__ float vsL[NB][TJ];
    __shared__ int   pmL[NB][TJ];

    const float* qsum = sums;
    const float* ksum = sums + NB * NL;
    const float* vsum = sums + 2 * NB * NL;

    const int it0 = blockIdx.x * TI;
    const int h   = blockIdx.y;
    const int tid = threadIdx.x;
    const int lane = tid & 63;
    const int wb   = tid >> 6;          // wave id == batch for PV
    const int lrow = lane & 15;
    const int kseg = (lane >> 4) * 16;  // byte offset within k of fragment

    // G/softmax mapping: 4 i x 2 j per thread
    const int gi = (tid >> 5) * 4;      // 0..28
    const int gj = (tid & 31) * 2;      // 0..62

    // ---- stage q_w tile transposed (once) + qsum ----
#pragma unroll
    for (int t = 0; t < 2; ++t) {
        int id = tid + 256 * t;
        int i = id >> 4, s4 = (id & 15) * 4;
        float4 x = *(const float4*)(q_w + ((size_t)(h * NL + it0 + i)) * HD + s4);
        qwT[s4 + 0][i] = x.x; qwT[s4 + 1][i] = x.y;
        qwT[s4 + 2][i] = x.z; qwT[s4 + 3][i] = x.w;
    }
    if (tid < 128) {
        int b = tid >> 5, i = tid & 31;
        qsL[b][i] = qsum[b * NL + it0 + i];
    }

    f32x4 acc[2][4];
#pragma unroll
    for (int m = 0; m < 2; ++m)
#pragma unroll
        for (int n = 0; n < 4; ++n) acc[m][n] = (f32x4){0.f, 0.f, 0.f, 0.f};

    for (int jt = 0; jt < NL / TJ; ++jt) {
        const int j0 = jt * TJ;
        __syncthreads();
        // ---- stage kwT (f32 [s][j]) ----
#pragma unroll
        for (int t = 0; t < 4; ++t) {
            int id = tid + 256 * t;
            int s = id >> 4, jj4 = (id & 15) * 4;
            *(float4*)&kwT[s][jj4] =
                *(const float4*)(k_wT + ((size_t)(h * HD + s)) * NL + j0 + jj4);
        }
        // ---- stage vTl (bf16 [t][j], swizzled) ----
#pragma unroll
        for (int t = 0; t < 2; ++t) {
            int id = tid + 256 * t;
            int r = id >> 3, u = id & 7;
            uint4 x = *(const uint4*)(v_wT + ((size_t)(h * HD + r)) * NL + j0 + u * 8);
            int off = (r * 128 + u * 16) ^ ((r & 7) << 4);
            *(uint4*)((char*)vTl + off) = x;
        }
        {
            int b = tid >> 6, jj = tid & 63;
            ksL[b][jj] = ksum[b * NL + j0 + jj];
            vsL[b][jj] = vsum[b * NL + j0 + jj];
            pmL[b][jj] = pad[b * NL + j0 + jj];
        }
        __syncthreads();

        // ---- G: 4x2 dot-products of length 64 ----
        float g[4][2];
#pragma unroll
        for (int a = 0; a < 4; ++a) { g[a][0] = 0.f; g[a][1] = 0.f; }
#pragma unroll 4
        for (int s = 0; s < HD; ++s) {
            const float4 qa = *(const float4*)&qwT[s][gi];
            const float2 kb = *(const float2*)&kwT[s][gj];
            g[0][0] = fmaf(qa.x, kb.x, g[0][0]); g[0][1] = fmaf(qa.x, kb.y, g[0][1]);
            g[1][0] = fmaf(qa.y, kb.x, g[1][0]); g[1][1] = fmaf(qa.y, kb.y, g[1][1]);
            g[2][0] = fmaf(qa.z, kb.x, g[2][0]); g[2][1] = fmaf(qa.z, kb.y, g[2][1]);
            g[3][0] = fmaf(qa.w, kb.x, g[3][0]); g[3][1] = fmaf(qa.w, kb.y, g[3][1]);
        }

        // ---- batch softmax -> bf16 weights*vsum into swizzled wlds ----
#pragma unroll
        for (int a = 0; a < 4; ++a) {
            const int il = gi + a;
            const int ig = it0 + il;
            float wv[2][4];
#pragma unroll
            for (int c = 0; c < 2; ++c) {
                const int jl = gj + c;
                const int jg = j0 + jl;
                const float gv = g[a][c] * 0.25f;
                const bool causal = jg > ig;
                float sb[4];
#pragma unroll
                for (int b = 0; b < 4; ++b)
                    sb[b] = (causal || pmL[b][jl]) ? FMIN_F32
                                                   : qsL[b][il] * ksL[b][jl] * gv;
                const float mx = fmaxf(fmaxf(sb[0], sb[1]), fmaxf(sb[2], sb[3]));
                float e[4], ssum = 0.f;
#pragma unroll
                for (int b = 0; b < 4; ++b) { e[b] = __expf(sb[b] - mx); ssum += e[b]; }
                const float inv = 1.0f / ssum;
#pragma unroll
                for (int b = 0; b < 4; ++b) wv[c][b] = e[b] * inv * vsL[b][jl];
            }
            const int base = (il * 128 + gj * 2) ^ ((il & 7) << 4);
#pragma unroll
            for (int b = 0; b < 4; ++b) {
                unsigned pk = (unsigned)f2bf(wv[0][b]) | ((unsigned)f2bf(wv[1][b]) << 16);
                *(unsigned*)((char*)wlds + b * 4096 + base) = pk;
            }
        }
        __syncthreads();

        // ---- PV via MFMA: wave wb computes heads[wb][32 i][64 t] ----
#pragma unroll
        for (int ks = 0; ks < 2; ++ks) {
            bf16x8 aF[2], bF[4];
#pragma unroll
            for (int m = 0; m < 2; ++m) {
                int row = m * 16 + lrow;
                int off = wb * 4096 + ((row * 128 + ks * 64 + kseg) ^ ((row & 7) << 4));
                aF[m] = __builtin_bit_cast(bf16x8, *(const uint4*)((const char*)wlds + off));
            }
#pragma unroll
            for (int n = 0; n < 4; ++n) {
                int row = n * 16 + lrow;
                int off = (row * 128 + ks * 64 + kseg) ^ ((row & 7) << 4);
                bF[n] = __builtin_bit_cast(bf16x8, *(const uint4*)((const char*)vTl + off));
            }
#pragma unroll
            for (int m = 0; m < 2; ++m)
#pragma unroll
                for (int n = 0; n < 4; ++n)
                    acc[m][n] = __builtin_amdgcn_mfma_f32_16x16x32_bf16(
                        aF[m], bF[n], acc[m][n], 0, 0, 0);
        }
    }

    // ---- store heads in out-GEMM A layout (bf16) ----
#pragma unroll
    for (int m = 0; m < 2; ++m)
#pragma unroll
        for (int n = 0; n < 4; ++n)
#pragma unroll
            for (int r = 0; r < 4; ++r) {
                int i  = it0 + m * 16 + (lane >> 4) * 4 + r;
                int tt = n * 16 + lrow;
                int rr = h * 64 + (i >> 4);
                int cc = (i & 15) * 64 + tt;
                headsA[((size_t)wb * NL + rr) * ND + cc] = f2bf(acc[m][n][r]);
            }
}

// ---------------------------------------------------------------------------
// Kernel 5: out[b] = headsA[b] (bf16 1024x1024) @ o_w  via o_wT, MFMA,
// 128x128 tile, BK=64, double-buffered swizzled LDS.
// ---------------------------------------------------------------------------
__global__ __launch_bounds__(256)
void outgemm_kernel(const unsigned short* __restrict__ headsA,
                    const unsigned short* __restrict__ o_wT,
                    float* __restrict__ out) {
    __shared__ __align__(16) unsigned short aL[2][128 * 64];
    __shared__ __align__(16) unsigned short bL[2][128 * 64];
    const int b  = blockIdx.z;
    const int i0 = blockIdx.y * 128;
    const int o0 = blockIdx.x * 128;
    const int tid  = threadIdx.x;
    const int lane = tid & 63;
    const int w    = tid >> 6;
    const int wr = (w >> 1) * 64, wc = (w & 1) * 64;
    const int lrow = lane & 15;
    const int kseg = (lane >> 4) * 16;
    const unsigned short* A = headsA + (size_t)b * NL * ND;

    f32x4 acc[4][4];
#pragma unroll
    for (int m = 0; m < 4; ++m)
#pragma unroll
        for (int n = 0; n < 4; ++n) acc[m][n] = (f32x4){0.f, 0.f, 0.f, 0.f};

    uint4 ra[4], rb[4];
    auto og_load = [&](int kt) {
#pragma unroll
        for (int t = 0; t < 4; ++t) {
            int id = tid + 256 * t;
            int r = id >> 3, u = id & 7;
            ra[t] = *(const uint4*)(A + ((size_t)(i0 + r)) * ND + kt * 64 + u * 8);
            rb[t] = *(const uint4*)(o_wT + ((size_t)(o0 + r)) * ND + kt * 64 + u * 8);
        }
    };
    auto og_write = [&](int buf) {
#pragma unroll
        for (int t = 0; t < 4; ++t) {
            int id = tid + 256 * t;
            int r = id >> 3, u = id & 7;
            int off = (r * 128 + u * 16) ^ ((r & 7) << 4);
            *(uint4*)((char*)aL[buf] + off) = ra[t];
            *(uint4*)((char*)bL[buf] + off) = rb[t];
        }
    };

    og_load(0);
    og_write(0);
    int cur = 0;
    for (int kt = 0; kt < 16; ++kt) {
        if (kt < 15) og_load(kt + 1);
        __syncthreads();
#pragma unroll
        for (int ks = 0; ks < 2; ++ks) {
            bf16x8 aF[4], bF[4];
#pragma unroll
            for (int m = 0; m < 4; ++m) {
                int row = wr + m * 16 + lrow;
                int off = (row * 128 + ks * 64 + kseg) ^ ((row & 7) << 4);
                aF[m] = __builtin_bit_cast(bf16x8, *(const uint4*)((const char*)aL[cur] + off));
            }
#pragma unroll
            for (int n = 0; n < 4; ++n) {
                int row = wc + n * 16 + lrow;
                int off = (row * 128 + ks * 64 + kseg) ^ ((row & 7) << 4);
                bF[n] = __builtin_bit_cast(bf16x8, *(const uint4*)((const char*)bL[cur] + off));
            }
#pragma unroll
            for (int m = 0; m < 4; ++m)
#pragma unroll
                for (int n = 0; n < 4; ++n)
                    acc[m][n] = __builtin_amdgcn_mfma_f32_16x16x32_bf16(
                        aF[m], bF[n], acc[m][n], 0, 0, 0);
        }
        if (kt < 15) og_write(cur ^ 1);
        cur ^= 1;
    }
#pragma unroll
    for (int m = 0; m < 4; ++m)
#pragma unroll
        for (int n = 0; n < 4; ++n)
#pragma unroll
            for (int r = 0; r < 4; ++r) {
                int i = i0 + wr + m * 16 + (lane >> 4) * 4 + r;
                int o = o0 + wc + n * 16 + lrow;
                out[((size_t)b * NL + i) * ND + o] = acc[m][n][r];
            }
}

// ---------------------------------------------------------------------------
extern "C" void kernel_launch(void* const* d_in, const int* in_sizes, int n_in,
                              void* d_out, int out_size, void* d_ws, size_t ws_size,
                              hipStream_t stream) {
    const float* query = (const float*)d_in[0];
    const float* key   = (const float*)d_in[1];
    const float* value = (const float*)d_in[2];
    const int*   pad   = (const int*)d_in[3];
    const float* q_w   = (const float*)d_in[4];
    const float* k_w   = (const float*)d_in[5];
    const float* v_w   = (const float*)d_in[6];
    const float* o_w   = (const float*)d_in[7];
    float* out = (float*)d_out;

    char* W = (char*)d_ws;
    float*          sums   = (float*)W;                    // 48 KB
    float*          k_wT   = (float*)(W + 49152);          // 4 MB f32 [h][s][j]
    unsigned short* v_wT   = (unsigned short*)(W + 4243456); // 2 MB bf16 [h][t][j]
    unsigned short* o_wT   = (unsigned short*)(W + 6340608); // 2 MB bf16 [o][c]
    unsigned short* headsA = (unsigned short*)(W + 8437760); // 8 MB bf16 [b][r][c]

    rowsum_kernel<<<3 * (NB * NL) / 4, 256, 0, stream>>>(query, key, value, sums);

    dim3 tg(NL / 64, NH);
    transKV_kernel<<<tg, 256, 0, stream>>>(k_w, v_w, k_wT, v_wT);

    dim3 og(ND / 64, ND / 64);
    transO_kernel<<<og, 256, 0, stream>>>(o_w, o_wT);

    dim3 ag(NL / 32, NH);
    attn_kernel<<<ag, 256, 0, stream>>>(q_w, pad, sums, k_wT, v_wT, headsA);

    dim3 gg(ND / 128, NL / 128, NB);
    outgemm_kernel<<<gg, 256, 0, stream>>>(headsA, o_wT, out);
}

// Round 3
// 116.405 us; speedup vs baseline: 3.4765x; 1.5459x over previous
//
#include <hip/hip_runtime.h>
#include <hip/hip_bf16.h>

#define NB 4
#define NL 1024
#define NH 16
#define ND 1024
#define HD 64
#define FMIN_F32 (-3.4028234663852886e38f)

typedef __bf16 bf16x8 __attribute__((ext_vector_type(8)));
typedef float f32x4 __attribute__((ext_vector_type(4)));

static __device__ inline unsigned short f2bf(float f) {
    __hip_bfloat16 h = __float2bfloat16(f);
    return __builtin_bit_cast(unsigned short, h);
}

// split f32 into bf16 hi + bf16 lo (x ~= hi + lo, error ~2^-18 rel)
static __device__ inline void bfsplit(float x, unsigned short& hi, unsigned short& lo) {
    unsigned u = __builtin_bit_cast(unsigned, x);
    unsigned r = (u + 0x7FFFu + ((u >> 16) & 1u)) >> 16;
    hi = (unsigned short)r;
    float hf = __builtin_bit_cast(float, r << 16);
    lo = f2bf(x - hf);
}

// ---------------------------------------------------------------------------
// Kernel 1: row sums of query/key/value.
// ---------------------------------------------------------------------------
__global__ __launch_bounds__(256)
void rowsum_kernel(const float* __restrict__ q, const float* __restrict__ k,
                   const float* __restrict__ v, float* __restrict__ out) {
    int gw   = blockIdx.x * 4 + (threadIdx.x >> 6);
    int lane = threadIdx.x & 63;
    int tensor = gw >> 12;
    int row    = gw & 4095;
    const float* src = tensor == 0 ? q : (tensor == 1 ? k : v);
    const float* p = src + (size_t)row * ND;
    float s = 0.f;
#pragma unroll
    for (int t = 0; t < 4; ++t) {
        float4 x = *reinterpret_cast<const float4*>(p + t * 256 + lane * 4);
        s += (x.x + x.y) + (x.z + x.w);
    }
#pragma unroll
    for (int off = 32; off; off >>= 1) s += __shfl_xor(s, off);
    if (lane == 0) out[tensor * (NB * NL) + row] = s;
}

// ---------------------------------------------------------------------------
// Kernel 2 (merged prep): blocks 0..255: v_w [h][j][t] -> v_wT bf16 [h][t][j]
//                         blocks 256..511: o_w [c][o] -> o_wT bf16 [o][c]
// ---------------------------------------------------------------------------
__global__ __launch_bounds__(256)
void prep_kernel(const float* __restrict__ v_w, const float* __restrict__ o_w,
                 unsigned short* __restrict__ v_wT, unsigned short* __restrict__ o_wT) {
    __shared__ float tile[64][68];
    const int tid = threadIdx.x;
    if (blockIdx.x < 256) {
        const int h  = blockIdx.x >> 4;
        const int j0 = (blockIdx.x & 15) * 64;
#pragma unroll
        for (int t = 0; t < 4; ++t) {
            int id = tid + 256 * t;
            int j = id >> 4, t4 = (id & 15) * 4;
            *(float4*)&tile[j][t4] =
                *(const float4*)(v_w + ((size_t)(h * NL + j0 + j)) * HD + t4);
        }
        __syncthreads();
#pragma unroll
        for (int t = 0; t < 4; ++t) {
            int id = tid + 256 * t;
            int tt = id >> 4, j4 = (id & 15) * 4;
            ushort4 u;
            u.x = f2bf(tile[j4 + 0][tt]); u.y = f2bf(tile[j4 + 1][tt]);
            u.z = f2bf(tile[j4 + 2][tt]); u.w = f2bf(tile[j4 + 3][tt]);
            *(ushort4*)(v_wT + ((size_t)(h * HD + tt)) * NL + j0 + j4) = u;
        }
    } else {
        const int bxo = blockIdx.x - 256;
        const int c0 = (bxo >> 4) * 64;
        const int o0 = (bxo & 15) * 64;
#pragma unroll
        for (int t = 0; t < 4; ++t) {
            int id = tid + 256 * t;
            int c = id >> 4, o4 = (id & 15) * 4;
            *(float4*)&tile[c][o4] =
                *(const float4*)(o_w + ((size_t)(c0 + c)) * ND + o0 + o4);
        }
        __syncthreads();
#pragma unroll
        for (int t = 0; t < 4; ++t) {
            int id = tid + 256 * t;
            int o = id >> 4, c4 = (id & 15) * 4;
            ushort4 u;
            u.x = f2bf(tile[c4 + 0][o]); u.y = f2bf(tile[c4 + 1][o]);
            u.z = f2bf(tile[c4 + 2][o]); u.w = f2bf(tile[c4 + 3][o]);
            *(ushort4*)(o_wT + ((size_t)(o0 + o)) * ND + c0 + c4) = u;
        }
    }
}

// ---------------------------------------------------------------------------
// Kernel 3: fused attn. G via bf16x3 MFMA, per-lane batch softmax, PV via MFMA.
// 512 threads (8 waves), TI=32, TJ=64. Grid (NL/32, NH).
// G-wave mapping: wave w -> (mi = w&1, nj = w>>1): 16x16 fragment of 32x64 tile.
// PV-wave mapping: wave w -> (batch = w>>1, mh = w&1): 16 i-rows x 64 t.
// ---------------------------------------------------------------------------
__global__ __launch_bounds__(512, 4)
void attn_kernel(const float* __restrict__ q_w, const float* __restrict__ k_w,
                 const int* __restrict__ pad, const float* __restrict__ sums,
                 const unsigned short* __restrict__ v_wT,
                 unsigned short* __restrict__ headsA) {
    __shared__ __align__(16) unsigned short qwHi[32 * 64], qwLo[32 * 64]; // [i][s] swz
    __shared__ __align__(16) unsigned short kwHi[64 * 64], kwLo[64 * 64]; // [j][s] swz
    __shared__ __align__(16) unsigned short vTl[64 * 64];                 // [t][j] swz
    __shared__ __align__(16) unsigned short wlds[NB * 32 * 64];           // [b][i][j] swz
    __shared__ __align__(16) float qs4[32 * 4];  // [i][b]
    __shared__ __align__(16) float ks4[64 * 4];  // [j][b]
    __shared__ __align__(16) float vs4[64 * 4];  // [j][b]
    __shared__ __align__(16) int   pm4[64 * 4];  // [j][b]

    const float* qsum = sums;
    const float* ksum = sums + NB * NL;
    const float* vsum = sums + 2 * NB * NL;

    const int it0 = blockIdx.x * 32;
    const int h   = blockIdx.y;
    const int tid  = threadIdx.x;
    const int lane = tid & 63;
    const int w    = tid >> 6;
    const int l15  = lane & 15;
    const int kb   = (lane >> 4) * 16;   // byte offset of k-segment within 64-elem row half

    // ---- stage q_w tile (f32 -> bf16 hi/lo), once ----
    {
        int row = tid >> 4;           // 0..31
        int s4  = (tid & 15) * 4;
        float4 x = *(const float4*)(q_w + ((size_t)(h * NL + it0 + row)) * HD + s4);
        unsigned short h0, h1, h2, h3, l0, l1, l2, l3;
        bfsplit(x.x, h0, l0); bfsplit(x.y, h1, l1);
        bfsplit(x.z, h2, l2); bfsplit(x.w, h3, l3);
        int off = (row * 128 + s4 * 2) ^ ((row & 7) << 4);
        *(uint2*)((char*)qwHi + off) = make_uint2((unsigned)h0 | ((unsigned)h1 << 16),
                                                  (unsigned)h2 | ((unsigned)h3 << 16));
        *(uint2*)((char*)qwLo + off) = make_uint2((unsigned)l0 | ((unsigned)l1 << 16),
                                                  (unsigned)l2 | ((unsigned)l3 << 16));
    }
    if (tid < 128) {
        int b = tid >> 5, i = tid & 31;
        qs4[i * 4 + b] = qsum[b * NL + it0 + i];
    }

    const int gmi = (w & 1) * 16;     // G fragment i-base
    const int gnj = (w >> 1) * 16;    // G fragment j-base
    const int pb  = w >> 1;           // PV batch
    const int pmh = (w & 1) * 16;     // PV i-half base

    f32x4 accP[4];
#pragma unroll
    for (int n = 0; n < 4; ++n) accP[n] = (f32x4){0.f, 0.f, 0.f, 0.f};

    for (int jt = 0; jt < NL / 64; ++jt) {
        const int j0 = jt * 64;
        __syncthreads();
        // ---- stage k_w (f32 -> bf16 hi/lo) ----
#pragma unroll
        for (int t = 0; t < 2; ++t) {
            int id = tid + 512 * t;
            int row = id >> 4;         // 0..63
            int s4  = (id & 15) * 4;
            float4 x = *(const float4*)(k_w + ((size_t)(h * NL + j0 + row)) * HD + s4);
            unsigned short h0, h1, h2, h3, l0, l1, l2, l3;
            bfsplit(x.x, h0, l0); bfsplit(x.y, h1, l1);
            bfsplit(x.z, h2, l2); bfsplit(x.w, h3, l3);
            int off = (row * 128 + s4 * 2) ^ ((row & 7) << 4);
            *(uint2*)((char*)kwHi + off) = make_uint2((unsigned)h0 | ((unsigned)h1 << 16),
                                                      (unsigned)h2 | ((unsigned)h3 << 16));
            *(uint2*)((char*)kwLo + off) = make_uint2((unsigned)l0 | ((unsigned)l1 << 16),
                                                      (unsigned)l2 | ((unsigned)l3 << 16));
        }
        // ---- stage vT (pre-converted bf16 [t][j]) ----
        {
            int t  = tid >> 3;          // 0..63
            int j8 = (tid & 7) * 8;
            uint4 x = *(const uint4*)(v_wT + ((size_t)(h * HD + t)) * NL + j0 + j8);
            int off = (t * 128 + j8 * 2) ^ ((t & 7) << 4);
            *(uint4*)((char*)vTl + off) = x;
        }
        if (tid < 256) {
            int b = tid >> 6, jj = tid & 63;
            ks4[jj * 4 + b] = ksum[b * NL + j0 + jj];
            vs4[jj * 4 + b] = vsum[b * NL + j0 + jj];
            pm4[jj * 4 + b] = pad[b * NL + j0 + jj];
        }
        __syncthreads();

        // ---- G: one 16x16 fragment per wave, bf16x3 ----
        f32x4 g = (f32x4){0.f, 0.f, 0.f, 0.f};
#pragma unroll
        for (int ks = 0; ks < 2; ++ks) {
            const int arow = gmi + l15;
            const int brow = gnj + l15;
            const int aoff = (arow * 128 + ks * 64 + kb) ^ ((arow & 7) << 4);
            const int boff = (brow * 128 + ks * 64 + kb) ^ ((brow & 7) << 4);
            bf16x8 aHi = __builtin_bit_cast(bf16x8, *(const uint4*)((const char*)qwHi + aoff));
            bf16x8 aLo = __builtin_bit_cast(bf16x8, *(const uint4*)((const char*)qwLo + aoff));
            bf16x8 bHi = __builtin_bit_cast(bf16x8, *(const uint4*)((const char*)kwHi + boff));
            bf16x8 bLo = __builtin_bit_cast(bf16x8, *(const uint4*)((const char*)kwLo + boff));
            g = __builtin_amdgcn_mfma_f32_16x16x32_bf16(aHi, bHi, g, 0, 0, 0);
            g = __builtin_amdgcn_mfma_f32_16x16x32_bf16(aLo, bHi, g, 0, 0, 0);
            g = __builtin_amdgcn_mfma_f32_16x16x32_bf16(aHi, bLo, g, 0, 0, 0);
        }

        // ---- per-lane 4-batch softmax -> bf16 weights*vsum into wlds ----
        {
            const int j  = gnj + l15;
            const int jg = j0 + j;
            const float4 ksv = *(const float4*)&ks4[j * 4];
            const float4 vsv = *(const float4*)&vs4[j * 4];
            const int4   pmv = *(const int4*)&pm4[j * 4];
#pragma unroll
            for (int r = 0; r < 4; ++r) {
                const int il = gmi + (lane >> 4) * 4 + r;
                const int ig = it0 + il;
                const float gv = g[r] * 0.25f;
                const float4 qsv = *(const float4*)&qs4[il * 4];
                const bool causal = jg > ig;
                const float sb0 = (causal || pmv.x) ? FMIN_F32 : qsv.x * ksv.x * gv;
                const float sb1 = (causal || pmv.y) ? FMIN_F32 : qsv.y * ksv.y * gv;
                const float sb2 = (causal || pmv.z) ? FMIN_F32 : qsv.z * ksv.z * gv;
                const float sb3 = (causal || pmv.w) ? FMIN_F32 : qsv.w * ksv.w * gv;
                const float mx = fmaxf(fmaxf(sb0, sb1), fmaxf(sb2, sb3));
                const float e0 = __expf(sb0 - mx);
                const float e1 = __expf(sb1 - mx);
                const float e2 = __expf(sb2 - mx);
                const float e3 = __expf(sb3 - mx);
                const float inv = __builtin_amdgcn_rcpf((e0 + e1) + (e2 + e3));
                const int off = (il * 128 + j * 2) ^ ((il & 7) << 4);
                *(unsigned short*)((char*)wlds + off)          = f2bf(e0 * inv * vsv.x);
                *(unsigned short*)((char*)wlds + 4096 + off)   = f2bf(e1 * inv * vsv.y);
                *(unsigned short*)((char*)wlds + 8192 + off)   = f2bf(e2 * inv * vsv.z);
                *(unsigned short*)((char*)wlds + 12288 + off)  = f2bf(e3 * inv * vsv.w);
            }
        }
        __syncthreads();

        // ---- PV: wave (pb, pmh): 16 i-rows x 64 t for batch pb ----
#pragma unroll
        for (int ks = 0; ks < 2; ++ks) {
            const int arow = pmh + l15;
            const int aoff = pb * 4096 + ((arow * 128 + ks * 64 + kb) ^ ((arow & 7) << 4));
            bf16x8 aF = __builtin_bit_cast(bf16x8, *(const uint4*)((const char*)wlds + aoff));
#pragma unroll
            for (int n = 0; n < 4; ++n) {
                const int vrow = n * 16 + l15;
                const int voff = (vrow * 128 + ks * 64 + kb) ^ ((vrow & 7) << 4);
                bf16x8 bF = __builtin_bit_cast(bf16x8, *(const uint4*)((const char*)vTl + voff));
                accP[n] = __builtin_amdgcn_mfma_f32_16x16x32_bf16(aF, bF, accP[n], 0, 0, 0);
            }
        }
    }

    // ---- store heads in out-GEMM A layout (bf16) ----
#pragma unroll
    for (int n = 0; n < 4; ++n)
#pragma unroll
        for (int r = 0; r < 4; ++r) {
            int i  = it0 + pmh + (lane >> 4) * 4 + r;
            int tt = n * 16 + l15;
            int rr = h * 64 + (i >> 4);
            int cc = (i & 15) * 64 + tt;
            headsA[((size_t)pb * NL + rr) * ND + cc] = f2bf(accP[n][r]);
        }
}

// ---------------------------------------------------------------------------
// Kernel 4: out[b] = headsA[b] (bf16 1024x1024) @ o_w via o_wT, MFMA,
// 128x128 tile, BK=64, double-buffered swizzled LDS.
// ---------------------------------------------------------------------------
__global__ __launch_bounds__(256)
void outgemm_kernel(const unsigned short* __restrict__ headsA,
                    const unsigned short* __restrict__ o_wT,
                    float* __restrict__ out) {
    __shared__ __align__(16) unsigned short aL[2][128 * 64];
    __shared__ __align__(16) unsigned short bL[2][128 * 64];
    const int b  = blockIdx.z;
    const int i0 = blockIdx.y * 128;
    const int o0 = blockIdx.x * 128;
    const int tid  = threadIdx.x;
    const int lane = tid & 63;
    const int w    = tid >> 6;
    const int wr = (w >> 1) * 64, wc = (w & 1) * 64;
    const int lrow = lane & 15;
    const int kseg = (lane >> 4) * 16;
    const unsigned short* A = headsA + (size_t)b * NL * ND;

    f32x4 acc[4][4];
#pragma unroll
    for (int m = 0; m < 4; ++m)
#pragma unroll
        for (int n = 0; n < 4; ++n) acc[m][n] = (f32x4){0.f, 0.f, 0.f, 0.f};

    uint4 ra[4], rb[4];
    auto og_load = [&](int kt) {
#pragma unroll
        for (int t = 0; t < 4; ++t) {
            int id = tid + 256 * t;
            int r = id >> 3, u = id & 7;
            ra[t] = *(const uint4*)(A + ((size_t)(i0 + r)) * ND + kt * 64 + u * 8);
            rb[t] = *(const uint4*)(o_wT + ((size_t)(o0 + r)) * ND + kt * 64 + u * 8);
        }
    };
    auto og_write = [&](int buf) {
#pragma unroll
        for (int t = 0; t < 4; ++t) {
            int id = tid + 256 * t;
            int r = id >> 3, u = id & 7;
            int off = (r * 128 + u * 16) ^ ((r & 7) << 4);
            *(uint4*)((char*)aL[buf] + off) = ra[t];
            *(uint4*)((char*)bL[buf] + off) = rb[t];
        }
    };

    og_load(0);
    og_write(0);
    int cur = 0;
    for (int kt = 0; kt < 16; ++kt) {
        if (kt < 15) og_load(kt + 1);
        __syncthreads();
#pragma unroll
        for (int ks = 0; ks < 2; ++ks) {
            bf16x8 aF[4], bF[4];
#pragma unroll
            for (int m = 0; m < 4; ++m) {
                int row = wr + m * 16 + lrow;
                int off = (row * 128 + ks * 64 + kseg) ^ ((row & 7) << 4);
                aF[m] = __builtin_bit_cast(bf16x8, *(const uint4*)((const char*)aL[cur] + off));
            }
#pragma unroll
            for (int n = 0; n < 4; ++n) {
                int row = wc + n * 16 + lrow;
                int off = (row * 128 + ks * 64 + kseg) ^ ((row & 7) << 4);
                bF[n] = __builtin_bit_cast(bf16x8, *(const uint4*)((const char*)bL[cur] + off));
            }
#pragma unroll
            for (int m = 0; m < 4; ++m)
#pragma unroll
                for (int n = 0; n < 4; ++n)
                    acc[m][n] = __builtin_amdgcn_mfma_f32_16x16x32_bf16(
                        aF[m], bF[n], acc[m][n], 0, 0, 0);
        }
        if (kt < 15) og_write(cur ^ 1);
        cur ^= 1;
    }
#pragma unroll
    for (int m = 0; m < 4; ++m)
#pragma unroll
        for (int n = 0; n < 4; ++n)
#pragma unroll
            for (int r = 0; r < 4; ++r) {
                int i = i0 + wr + m * 16 + (lane >> 4) * 4 + r;
                int o = o0 + wc + n * 16 + lrow;
                out[((size_t)b * NL + i) * ND + o] = acc[m][n][r];
            }
}

// ---------------------------------------------------------------------------
extern "C" void kernel_launch(void* const* d_in, const int* in_sizes, int n_in,
                              void* d_out, int out_size, void* d_ws, size_t ws_size,
                              hipStream_t stream) {
    const float* query = (const float*)d_in[0];
    const float* key   = (const float*)d_in[1];
    const float* value = (const float*)d_in[2];
    const int*   pad   = (const int*)d_in[3];
    const float* q_w   = (const float*)d_in[4];
    const float* k_w   = (const float*)d_in[5];
    const float* v_w   = (const float*)d_in[6];
    const float* o_w   = (const float*)d_in[7];
    float* out = (float*)d_out;

    char* W = (char*)d_ws;
    float*          sums   = (float*)W;                       // 48 KB
    unsigned short* v_wT   = (unsigned short*)(W + 49152);    // 2 MB bf16 [h][t][j]
    unsigned short* o_wT   = (unsigned short*)(W + 2146304);  // 2 MB bf16 [o][c]
    unsigned short* headsA = (unsigned short*)(W + 4243456);  // 8 MB bf16 [b][r][c]

    rowsum_kernel<<<3 * (NB * NL) / 4, 256, 0, stream>>>(query, key, value, sums);

    prep_kernel<<<512, 256, 0, stream>>>(v_w, o_w, v_wT, o_wT);

    dim3 ag(NL / 32, NH);
    attn_kernel<<<ag, 512, 0, stream>>>(q_w, k_w, pad, sums, v_wT, headsA);

    dim3 gg(ND / 128, NL / 128, NB);
    outgemm_kernel<<<gg, 256, 0, stream>>>(headsA, o_wT, out);
}

// Round 4
// 83.934 us; speedup vs baseline: 4.8215x; 1.3869x over previous
//
#include <hip/hip_runtime.h>
#include <hip/hip_bf16.h>

#define NB 4
#define NL 1024
#define NH 16
#define ND 1024
#define HD 64
#define FMIN_F32 (-3.4028234663852886e38f)

typedef __bf16 bf16x8 __attribute__((ext_vector_type(8)));
typedef float f32x4 __attribute__((ext_vector_type(4)));
typedef unsigned int u32;

static __device__ inline unsigned short f2bf(float f) {
    __hip_bfloat16 h = __float2bfloat16(f);
    return __builtin_bit_cast(unsigned short, h);
}

// split f32 into bf16 hi + bf16 lo (x ~= hi + lo, error ~2^-18 rel)
static __device__ inline void bfsplit(float x, unsigned short& hi, unsigned short& lo) {
    unsigned u = __builtin_bit_cast(unsigned, x);
    unsigned r = (u + 0x7FFFu + ((u >> 16) & 1u)) >> 16;
    hi = (unsigned short)r;
    float hf = __builtin_bit_cast(float, r << 16);
    lo = f2bf(x - hf);
}

// async global->LDS, 16B per lane. LDS dest = firstlane(lds)+lane*16.
static __device__ __forceinline__ void gload16(void* lds, const void* g) {
    __builtin_amdgcn_global_load_lds(
        (const __attribute__((address_space(1))) u32*)g,
        (__attribute__((address_space(3))) u32*)lds, 16, 0, 0);
}

// ---------------------------------------------------------------------------
// Kernel 1: row sums of query/key/value.
// ---------------------------------------------------------------------------
__global__ __launch_bounds__(256)
void rowsum_kernel(const float* __restrict__ q, const float* __restrict__ k,
                   const float* __restrict__ v, float* __restrict__ out) {
    int gw   = blockIdx.x * 4 + (threadIdx.x >> 6);
    int lane = threadIdx.x & 63;
    int tensor = gw >> 12;
    int row    = gw & 4095;
    const float* src = tensor == 0 ? q : (tensor == 1 ? k : v);
    const float* p = src + (size_t)row * ND;
    float s = 0.f;
#pragma unroll
    for (int t = 0; t < 4; ++t) {
        float4 x = *reinterpret_cast<const float4*>(p + t * 256 + lane * 4);
        s += (x.x + x.y) + (x.z + x.w);
    }
#pragma unroll
    for (int off = 32; off; off >>= 1) s += __shfl_xor(s, off);
    if (lane == 0) out[tensor * (NB * NL) + row] = s;
}

// ---------------------------------------------------------------------------
// Kernel 2: prep — pre-swizzled operand tiles (LDS-image order in HBM).
// Swizzle: byte ^= ((row&7)<<4) within each row-major [R][64] bf16 tile.
//  blocks [0,256):   k_w  -> kPhi/kPlo  [h][jt] 8KB tiles, (j_local, s)
//  blocks [256,512): v_w  -> vP         [h][jt] 8KB tiles, (t, j_local)   (transposed)
//  blocks [512,640): o_w  -> BP         [ot][kt] 16KB tiles, (o_local, c_local) (transposed)
// ---------------------------------------------------------------------------
__global__ __launch_bounds__(256)
void prep_kernel(const float* __restrict__ k_w, const float* __restrict__ v_w,
                 const float* __restrict__ o_w,
                 unsigned short* __restrict__ kPhi, unsigned short* __restrict__ kPlo,
                 unsigned short* __restrict__ vP, unsigned short* __restrict__ BP) {
    __shared__ float tile[64][132];
    const int tid = threadIdx.x;
    const int bx  = blockIdx.x;
    if (bx < 256) {
        const int h = bx >> 4, jt = bx & 15;
        char* hiT = (char*)kPhi + (size_t)(h * 16 + jt) * 8192;
        char* loT = (char*)kPlo + (size_t)(h * 16 + jt) * 8192;
        const int row = tid >> 2;
        const int s0  = (tid & 3) * 16;
        const float* src = k_w + ((size_t)(h * NL + jt * 64 + row)) * HD + s0;
#pragma unroll
        for (int t = 0; t < 4; ++t) {
            float4 x = reinterpret_cast<const float4*>(src)[t];
            unsigned short h0, h1, h2, h3, l0, l1, l2, l3;
            bfsplit(x.x, h0, l0); bfsplit(x.y, h1, l1);
            bfsplit(x.z, h2, l2); bfsplit(x.w, h3, l3);
            int off = (row * 128 + (s0 + 4 * t) * 2) ^ ((row & 7) << 4);
            *(uint2*)(hiT + off) = make_uint2((u32)h0 | ((u32)h1 << 16),
                                              (u32)h2 | ((u32)h3 << 16));
            *(uint2*)(loT + off) = make_uint2((u32)l0 | ((u32)l1 << 16),
                                              (u32)l2 | ((u32)l3 << 16));
        }
    } else if (bx < 512) {
        const int h = (bx - 256) >> 4, jt = (bx - 256) & 15;
#pragma unroll
        for (int t = 0; t < 4; ++t) {
            int id = tid + 256 * t;
            int j = id >> 4, t4 = (id & 15) * 4;
            *(float4*)&tile[j][t4] =
                *(const float4*)(v_w + ((size_t)(h * NL + jt * 64 + j)) * HD + t4);
        }
        __syncthreads();
        char* vT_ = (char*)vP + (size_t)(h * 16 + jt) * 8192;
        const int trow = tid >> 2;
        const int jq   = (tid & 3) * 16;
#pragma unroll
        for (int q = 0; q < 4; ++q) {
            int j4 = jq + 4 * q;
            uint2 u;
            u.x = (u32)f2bf(tile[j4 + 0][trow]) | ((u32)f2bf(tile[j4 + 1][trow]) << 16);
            u.y = (u32)f2bf(tile[j4 + 2][trow]) | ((u32)f2bf(tile[j4 + 3][trow]) << 16);
            int off = (trow * 128 + j4 * 2) ^ ((trow & 7) << 4);
            *(uint2*)(vT_ + off) = u;
        }
    } else {
        const int bxo = bx - 512;
        const int ot = bxo >> 4, kt = bxo & 15;
#pragma unroll
        for (int t = 0; t < 8; ++t) {
            int id = tid + 256 * t;
            int c = id >> 5, o4 = (id & 31) * 4;
            *(float4*)&tile[c][o4] =
                *(const float4*)(o_w + ((size_t)(kt * 64 + c)) * ND + ot * 128 + o4);
        }
        __syncthreads();
        char* bT = (char*)BP + (size_t)(ot * 16 + kt) * 16384;
#pragma unroll
        for (int t = 0; t < 8; ++t) {
            int id = tid + 256 * t;
            int ol = id >> 4, c4 = (id & 15) * 4;
            uint2 u;
            u.x = (u32)f2bf(tile[c4 + 0][ol]) | ((u32)f2bf(tile[c4 + 1][ol]) << 16);
            u.y = (u32)f2bf(tile[c4 + 2][ol]) | ((u32)f2bf(tile[c4 + 3][ol]) << 16);
            int off = (ol * 128 + c4 * 2) ^ ((ol & 7) << 4);
            *(uint2*)(bT + off) = u;
        }
    }
}

// ---------------------------------------------------------------------------
// Kernel 3: fused attn. G via bf16x3 MFMA, per-lane batch softmax, PV via MFMA.
// 512 threads (8 waves), TI=32, TJ=64, double-buffered gload_lds staging.
// Writes AP (pre-swizzled out-GEMM A tiles): tile (b, h, kt=i&15), row ib=i>>4, col t.
// ---------------------------------------------------------------------------
__global__ __launch_bounds__(512, 4)
void attn_kernel(const float* __restrict__ q_w, const int* __restrict__ pad,
                 const float* __restrict__ sums,
                 const unsigned short* __restrict__ kPhi,
                 const unsigned short* __restrict__ kPlo,
                 const unsigned short* __restrict__ vP,
                 unsigned short* __restrict__ AP) {
    __shared__ __align__(16) unsigned short kHi[2][4096], kLo[2][4096], vTl[2][4096];
    __shared__ __align__(16) unsigned short qHi[2048], qLo[2048];
    __shared__ __align__(16) unsigned short wlds[8192];
    __shared__ __align__(16) float qs4[128];
    __shared__ __align__(16) float ks4[2][256];
    __shared__ __align__(16) float vs4[2][256];
    __shared__ __align__(16) int   pm4[2][256];

    const float* qsum = sums;
    const float* ksum = sums + NB * NL;
    const float* vsum = sums + 2 * NB * NL;

    const int it0 = blockIdx.x * 32;
    const int h   = blockIdx.y;
    const int tid  = threadIdx.x;
    const int lane = tid & 63;
    const int w    = tid >> 6;
    const int l15  = lane & 15;
    const int kb   = (lane >> 4) * 16;

    // ---- stage q tile (f32 -> bf16 hi/lo, swizzled), once ----
    {
        int row = tid >> 4;
        int s4  = (tid & 15) * 4;
        float4 x = *(const float4*)(q_w + ((size_t)(h * NL + it0 + row)) * HD + s4);
        unsigned short h0, h1, h2, h3, l0, l1, l2, l3;
        bfsplit(x.x, h0, l0); bfsplit(x.y, h1, l1);
        bfsplit(x.z, h2, l2); bfsplit(x.w, h3, l3);
        int off = (row * 128 + s4 * 2) ^ ((row & 7) << 4);
        *(uint2*)((char*)qHi + off) = make_uint2((u32)h0 | ((u32)h1 << 16),
                                                 (u32)h2 | ((u32)h3 << 16));
        *(uint2*)((char*)qLo + off) = make_uint2((u32)l0 | ((u32)l1 << 16),
                                                 (u32)l2 | ((u32)l3 << 16));
    }
    if (tid < 128) {
        int b = tid >> 5, i = tid & 31;
        qs4[i * 4 + b] = qsum[b * NL + it0 + i];
    }

    auto stage = [&](int buf, int jt) {
        const size_t tb = (size_t)(h * 16 + jt) * 8192 + tid * 16;
        gload16((char*)kHi[buf] + tid * 16, (const char*)kPhi + tb);
        gload16((char*)kLo[buf] + tid * 16, (const char*)kPlo + tb);
        gload16((char*)vTl[buf] + tid * 16, (const char*)vP + tb);
        if (tid < 256) {
            int b = tid >> 6, jj = tid & 63;
            ks4[buf][jj * 4 + b] = ksum[b * NL + jt * 64 + jj];
            vs4[buf][jj * 4 + b] = vsum[b * NL + jt * 64 + jj];
            pm4[buf][jj * 4 + b] = pad[b * NL + jt * 64 + jj];
        }
    };

    const int gmi = (w & 1) * 16;
    const int gnj = (w >> 1) * 16;
    const int pb  = w >> 1;
    const int pmh = (w & 1) * 16;

    f32x4 accP[4];
#pragma unroll
    for (int n = 0; n < 4; ++n) accP[n] = (f32x4){0.f, 0.f, 0.f, 0.f};

    stage(0, 0);
    __syncthreads();
    int cur = 0;

    for (int jt = 0; jt < 16; ++jt) {
        const int j0 = jt * 64;
        if (jt < 15) stage(cur ^ 1, jt + 1);

        // ---- G: one 16x16 fragment per wave, bf16x3 ----
        f32x4 g = (f32x4){0.f, 0.f, 0.f, 0.f};
#pragma unroll
        for (int ks = 0; ks < 2; ++ks) {
            const int arow = gmi + l15;
            const int brow = gnj + l15;
            const int aoff = (arow * 128 + ks * 64 + kb) ^ ((arow & 7) << 4);
            const int boff = (brow * 128 + ks * 64 + kb) ^ ((brow & 7) << 4);
            bf16x8 aHi = __builtin_bit_cast(bf16x8, *(const uint4*)((const char*)qHi + aoff));
            bf16x8 aLo = __builtin_bit_cast(bf16x8, *(const uint4*)((const char*)qLo + aoff));
            bf16x8 bHi = __builtin_bit_cast(bf16x8, *(const uint4*)((const char*)kHi[cur] + boff));
            bf16x8 bLo = __builtin_bit_cast(bf16x8, *(const uint4*)((const char*)kLo[cur] + boff));
            g = __builtin_amdgcn_mfma_f32_16x16x32_bf16(aHi, bHi, g, 0, 0, 0);
            g = __builtin_amdgcn_mfma_f32_16x16x32_bf16(aLo, bHi, g, 0, 0, 0);
            g = __builtin_amdgcn_mfma_f32_16x16x32_bf16(aHi, bLo, g, 0, 0, 0);
        }

        // ---- per-lane 4-batch softmax -> bf16 weights*vsum into wlds ----
        {
            const int j  = gnj + l15;
            const int jg = j0 + j;
            const float4 ksv = *(const float4*)&ks4[cur][j * 4];
            const float4 vsv = *(const float4*)&vs4[cur][j * 4];
            const int4   pmv = *(const int4*)&pm4[cur][j * 4];
#pragma unroll
            for (int r = 0; r < 4; ++r) {
                const int il = gmi + (lane >> 4) * 4 + r;
                const int ig = it0 + il;
                const float gv = g[r] * 0.25f;
                const float4 qsv = *(const float4*)&qs4[il * 4];
                const bool causal = jg > ig;
                const float sb0 = (causal || pmv.x) ? FMIN_F32 : qsv.x * ksv.x * gv;
                const float sb1 = (causal || pmv.y) ? FMIN_F32 : qsv.y * ksv.y * gv;
                const float sb2 = (causal || pmv.z) ? FMIN_F32 : qsv.z * ksv.z * gv;
                const float sb3 = (causal || pmv.w) ? FMIN_F32 : qsv.w * ksv.w * gv;
                const float mx = fmaxf(fmaxf(sb0, sb1), fmaxf(sb2, sb3));
                const float e0 = __expf(sb0 - mx);
                const float e1 = __expf(sb1 - mx);
                const float e2 = __expf(sb2 - mx);
                const float e3 = __expf(sb3 - mx);
                const float inv = __builtin_amdgcn_rcpf((e0 + e1) + (e2 + e3));
                const int off = (il * 128 + j * 2) ^ ((il & 7) << 4);
                *(unsigned short*)((char*)wlds + off)         = f2bf(e0 * inv * vsv.x);
                *(unsigned short*)((char*)wlds + 4096 + off)  = f2bf(e1 * inv * vsv.y);
                *(unsigned short*)((char*)wlds + 8192 + off)  = f2bf(e2 * inv * vsv.z);
                *(unsigned short*)((char*)wlds + 12288 + off) = f2bf(e3 * inv * vsv.w);
            }
        }
        __syncthreads();   // wlds ready; jt+1 staging drained

        // ---- PV: wave (pb, pmh): 16 i-rows x 64 t for batch pb ----
#pragma unroll
        for (int ks = 0; ks < 2; ++ks) {
            const int arow = pmh + l15;
            const int aoff = pb * 4096 + ((arow * 128 + ks * 64 + kb) ^ ((arow & 7) << 4));
            bf16x8 aF = __builtin_bit_cast(bf16x8, *(const uint4*)((const char*)wlds + aoff));
#pragma unroll
            for (int n = 0; n < 4; ++n) {
                const int vrow = n * 16 + l15;
                const int voff = (vrow * 128 + ks * 64 + kb) ^ ((vrow & 7) << 4);
                bf16x8 bF = __builtin_bit_cast(bf16x8, *(const uint4*)((const char*)vTl[cur] + voff));
                accP[n] = __builtin_amdgcn_mfma_f32_16x16x32_bf16(aF, bF, accP[n], 0, 0, 0);
            }
        }
        __syncthreads();   // PV done reading wlds/vTl before next overwrite
        cur ^= 1;
    }

    // ---- store AP tiles (pre-swizzled out-GEMM A layout, bf16) ----
    {
        const int ib = (it0 + pmh) >> 4;   // constant per thread
        char* tbase = (char*)AP + (size_t)((pb * 16 + h) * 16) * 8192;
#pragma unroll
        for (int n = 0; n < 4; ++n)
#pragma unroll
            for (int r = 0; r < 4; ++r) {
                int kt = (lane >> 4) * 4 + r;   // i & 15
                int tt = n * 16 + l15;
                int off = (ib * 128 + tt * 2) ^ ((ib & 7) << 4);
                *(unsigned short*)(tbase + (size_t)kt * 8192 + off) = f2bf(accP[n][r]);
            }
    }
}

// ---------------------------------------------------------------------------
// Kernel 4: out(4096x1024) = AP(4096x1024 bf16) @ BP(1024x1024 bf16 [o][c]^T).
// 64x128 tiles, grid (8, 64) = 512 blocks, 256 threads, BK=64, dbuf gload_lds.
// ---------------------------------------------------------------------------
__global__ __launch_bounds__(256, 2)
void outgemm_kernel(const unsigned short* __restrict__ AP,
                    const unsigned short* __restrict__ BP,
                    float* __restrict__ out) {
    __shared__ __align__(16) unsigned short aL[2][4096];   // 8KB per buf
    __shared__ __align__(16) unsigned short bL[2][8192];   // 16KB per buf
    const int ox = blockIdx.x;     // 0..7  (128-col o tiles)
    const int my = blockIdx.y;     // 0..63 (64-row panels)
    const int tid  = threadIdx.x;
    const int lane = tid & 63;
    const int w    = tid >> 6;
    const int wr = (w & 1) * 32;
    const int wc = (w >> 1) * 64;
    const int l15  = lane & 15;
    const int kseg = (lane >> 4) * 16;

    f32x4 acc[2][4];
#pragma unroll
    for (int m = 0; m < 2; ++m)
#pragma unroll
        for (int n = 0; n < 4; ++n) acc[m][n] = (f32x4){0.f, 0.f, 0.f, 0.f};

    auto stage = [&](int buf, int kt) {
        const char* at = (const char*)AP + (size_t)(my * 16 + kt) * 8192;
        const char* bt = (const char*)BP + (size_t)(ox * 16 + kt) * 16384;
        gload16((char*)aL[buf] + tid * 16, at + tid * 16);
        gload16((char*)aL[buf] + 4096 + tid * 16, at + 4096 + tid * 16);
#pragma unroll
        for (int r = 0; r < 4; ++r)
            gload16((char*)bL[buf] + r * 4096 + tid * 16, bt + r * 4096 + tid * 16);
    };

    stage(0, 0);
    __syncthreads();
    int cur = 0;
    for (int kt = 0; kt < 16; ++kt) {
        if (kt < 15) stage(cur ^ 1, kt + 1);
#pragma unroll
        for (int ks = 0; ks < 2; ++ks) {
            bf16x8 aF[2], bF[4];
#pragma unroll
            for (int m = 0; m < 2; ++m) {
                int row = wr + m * 16 + l15;
                int off = (row * 128 + ks * 64 + kseg) ^ ((row & 7) << 4);
                aF[m] = __builtin_bit_cast(bf16x8, *(const uint4*)((const char*)aL[cur] + off));
            }
#pragma unroll
            for (int n = 0; n < 4; ++n) {
                int row = wc + n * 16 + l15;
                int off = (row * 128 + ks * 64 + kseg) ^ ((row & 7) << 4);
                bF[n] = __builtin_bit_cast(bf16x8, *(const uint4*)((const char*)bL[cur] + off));
            }
#pragma unroll
            for (int m = 0; m < 2; ++m)
#pragma unroll
                for (int n = 0; n < 4; ++n)
                    acc[m][n] = __builtin_amdgcn_mfma_f32_16x16x32_bf16(
                        aF[m], bF[n], acc[m][n], 0, 0, 0);
        }
        __syncthreads();
        cur ^= 1;
    }
#pragma unroll
    for (int m = 0; m < 2; ++m)
#pragma unroll
        for (int n = 0; n < 4; ++n)
#pragma unroll
            for (int r = 0; r < 4; ++r) {
                int row = my * 64 + wr + m * 16 + (lane >> 4) * 4 + r;
                int col = ox * 128 + wc + n * 16 + l15;
                out[(size_t)row * ND + col] = acc[m][n][r];
            }
}

// ---------------------------------------------------------------------------
extern "C" void kernel_launch(void* const* d_in, const int* in_sizes, int n_in,
                              void* d_out, int out_size, void* d_ws, size_t ws_size,
                              hipStream_t stream) {
    const float* query = (const float*)d_in[0];
    const float* key   = (const float*)d_in[1];
    const float* value = (const float*)d_in[2];
    const int*   pad   = (const int*)d_in[3];
    const float* q_w   = (const float*)d_in[4];
    const float* k_w   = (const float*)d_in[5];
    const float* v_w   = (const float*)d_in[6];
    const float* o_w   = (const float*)d_in[7];
    float* out = (float*)d_out;

    char* W = (char*)d_ws;
    float*          sums = (float*)W;                        // 48 KB
    unsigned short* kPhi = (unsigned short*)(W + 49152);     // 2 MB
    unsigned short* kPlo = (unsigned short*)(W + 2146304);   // 2 MB
    unsigned short* vP   = (unsigned short*)(W + 4243456);   // 2 MB
    unsigned short* BP   = (unsigned short*)(W + 6340608);   // 2 MB
    unsigned short* AP   = (unsigned short*)(W + 8437760);   // 8 MB

    rowsum_kernel<<<3 * (NB * NL) / 4, 256, 0, stream>>>(query, key, value, sums);

    prep_kernel<<<640, 256, 0, stream>>>(k_w, v_w, o_w, kPhi, kPlo, vP, BP);

    dim3 ag(NL / 32, NH);
    attn_kernel<<<ag, 512, 0, stream>>>(q_w, pad, sums, kPhi, kPlo, vP, AP);

    dim3 gg(8, 64);
    outgemm_kernel<<<gg, 256, 0, stream>>>(AP, BP, out);
}